// Round 2
// 988.429 us; speedup vs baseline: 1.1382x; 1.1382x over previous
//
#include <hip/hip_runtime.h>
#include <hip/hip_bf16.h>
#include <math.h>

// ---------------------------------------------------------------------------
// GCN 2-layer forward, CSR aggregation + bf16 MFMA GEMM1 + bf16 activations.
// CSR build uses a two-phase bucketed counting sort (bucket = 512 dst nodes).
// R5: spmm1/spmm2 restructured for memory-level parallelism — the serial
// one-edge-per-step broadcast loop was latency-bound (VALUBusy 31%, HBM 43%,
// no pipe saturated). spmm1: 2 edges/step (wave halves) x uint4 loads x4
// unroll = 8 edges in flight. spmm2: 3 edge-groups of 20 lanes x2 unroll.
// R6: fix macro-parameter capture of '.w' member in ACC8 (compile error).
// ---------------------------------------------------------------------------

#define NFEAT 512
#define NHID  256
#define NCLASS 40
#define BKT_SHIFT 9
#define BKT_NODES 512
#define MAX_BKT 256      // >= ceil(100000/512)=196
#define BIN_EPB 4096     // edges per binA block

typedef __attribute__((ext_vector_type(4))) float f32x4;
typedef __attribute__((ext_vector_type(8))) short s16x8;

__device__ __forceinline__ ushort f2bf(float f) {
  unsigned u = __float_as_uint(f);
  u = (u + 0x7fffu + ((u >> 16) & 1u)) >> 16;  // RNE
  return (ushort)u;
}
__device__ __forceinline__ float bflo(unsigned u) {
  return __uint_as_float(u << 16);
}
__device__ __forceinline__ float bfhi(unsigned u) {
  return __uint_as_float(u & 0xffff0000u);
}

// -------------------- W1 transpose+convert: [512][256] -> bf16 [256][512] --
__global__ __launch_bounds__(256) void w1t_kernel(const float* __restrict__ W1,
                                                  ushort* __restrict__ Bt) {
  int idx = blockIdx.x * 256 + threadIdx.x;
  int k = idx >> 8, n = idx & 255;
  Bt[n * NFEAT + k] = f2bf(W1[idx]);
}

// ------------------------- GEMM1: bf16 MFMA -------------------------------
#define LDK 40  // padded LDS k-stride (bf16): max 2-way bank aliasing (free)
__global__ __launch_bounds__(256) void gemm1_mfma(
    const float* __restrict__ A, const ushort* __restrict__ Bt,
    ushort* __restrict__ C, int M) {
  __shared__ ushort As[128 * LDK];
  __shared__ ushort Bs[128 * LDK];
  int tid = threadIdx.x;
  int wave = tid >> 6, lane = tid & 63;
  int bm = blockIdx.y * 128;
  int bn = blockIdx.x * 128;
  int wm = (wave & 1) * 64, wn = (wave >> 1) * 64;
  int lm = lane & 15;
  int lk = (lane >> 4) * 8;

  int arow = tid >> 1;
  int ahalf = (tid & 1) * 16;
  int brow = tid >> 2;
  int bq = (tid & 3) * 8;

  f32x4 acc[4][4] = {};

  const bool arv = (bm + arow) < M;
  const float* aptr = A + (size_t)(bm + arow) * NFEAT + ahalf;
  ushort* asp = &As[arow * LDK + ahalf];

  for (int k0 = 0; k0 < NFEAT; k0 += 32) {
#pragma unroll
    for (int q = 0; q < 4; ++q) {
      float4 v = arv ? *(const float4*)(aptr + k0 + q * 4)
                     : make_float4(0.f, 0.f, 0.f, 0.f);
      ushort4 b;
      b.x = f2bf(v.x); b.y = f2bf(v.y); b.z = f2bf(v.z); b.w = f2bf(v.w);
      *(ushort4*)(asp + q * 4) = b;
    }
#pragma unroll
    for (int p = 0; p < 2; ++p) {
      int n = p * 64 + brow;
      *(uint4*)&Bs[n * LDK + bq] =
          *(const uint4*)&Bt[(size_t)(bn + n) * NFEAT + k0 + bq];
    }
    __syncthreads();
    s16x8 afr[4], bfr[4];
#pragma unroll
    for (int i = 0; i < 4; ++i)
      afr[i] = *(const s16x8*)&As[(wm + i * 16 + lm) * LDK + lk];
#pragma unroll
    for (int j = 0; j < 4; ++j)
      bfr[j] = *(const s16x8*)&Bs[(wn + j * 16 + lm) * LDK + lk];
#pragma unroll
    for (int i = 0; i < 4; ++i)
#pragma unroll
      for (int j = 0; j < 4; ++j)
        acc[i][j] = __builtin_amdgcn_mfma_f32_16x16x32_bf16(afr[i], bfr[j],
                                                            acc[i][j], 0, 0, 0);
    __syncthreads();
  }
  int ocol = bn + wn + lm;
  int orow0 = bm + wm + (lane >> 4) * 4;
#pragma unroll
  for (int i = 0; i < 4; ++i) {
#pragma unroll
    for (int r = 0; r < 4; ++r) {
      int row = orow0 + i * 16 + r;
      if (row < M) {
#pragma unroll
        for (int j = 0; j < 4; ++j)
          C[(size_t)row * NHID + ocol + j * 16] = f2bf(acc[i][j][r]);
      }
    }
  }
}

// ------------------------- CSR build --------------------------------------
__global__ __launch_bounds__(256) void hist_kernel(const int* __restrict__ dst,
                                                   int* __restrict__ deg, int E) {
  int e = blockIdx.x * 256 + threadIdx.x;
  if (e < E) atomicAdd(&deg[dst[e]], 1);
}

__global__ __launch_bounds__(256) void scan1_kernel(const int* __restrict__ deg,
                                                    int* __restrict__ part,
                                                    int* __restrict__ bsums, int M) {
  __shared__ int tmp[256];
  int t = threadIdx.x;
  int i = blockIdx.x * 256 + t;
  int v = (i < M) ? deg[i] : 0;
  tmp[t] = v;
  __syncthreads();
  for (int off = 1; off < 256; off <<= 1) {
    int add = (t >= off) ? tmp[t - off] : 0;
    __syncthreads();
    tmp[t] += add;
    __syncthreads();
  }
  if (i < M) part[i] = tmp[t];
  if (t == 255) bsums[blockIdx.x] = tmp[255];
}

__global__ __launch_bounds__(512) void scan2_kernel(int* __restrict__ bsums, int nb) {
  __shared__ int tmp[512];
  int t = threadIdx.x;
  int v = (t < nb) ? bsums[t] : 0;
  tmp[t] = v;
  __syncthreads();
  for (int off = 1; off < 512; off <<= 1) {
    int add = (t >= off) ? tmp[t - off] : 0;
    __syncthreads();
    tmp[t] += add;
    __syncthreads();
  }
  if (t < nb) bsums[t] = tmp[t];
}

__global__ __launch_bounds__(256) void scan3_kernel(
    const int* __restrict__ part, const int* __restrict__ bsums,
    const int* __restrict__ deg, int* __restrict__ rowptr, int M) {
  int i = blockIdx.x * 256 + threadIdx.x;
  if (i >= M) return;
  int incl = part[i] + (blockIdx.x > 0 ? bsums[blockIdx.x - 1] : 0);
  rowptr[i] = incl - deg[i];
}

// bucket cursors: gcursor[b] = rowptr[b*512]
__global__ __launch_bounds__(256) void initcur_kernel(
    const int* __restrict__ rowptr, int* __restrict__ gcursor, int nbkt) {
  int b = threadIdx.x;
  if (b < nbkt) gcursor[b] = rowptr[b * BKT_NODES];
}

// binA: bucket-major binning. Per-block LDS histogram -> one global reserve
// per (block,bucket) -> write (src,w) int2 + dst-low ushort into tmp.
__global__ __launch_bounds__(256) void binA_kernel(
    const int* __restrict__ esrc, const int* __restrict__ edst,
    const float* __restrict__ ew, int* __restrict__ gcursor,
    int2* __restrict__ tmp_sw, ushort* __restrict__ tmp_d, int E) {
  __shared__ int hist[MAX_BKT];
  int t = threadIdx.x;
  for (int i = t; i < MAX_BKT; i += 256) hist[i] = 0;
  __syncthreads();
  int e0 = blockIdx.x * BIN_EPB;
#pragma unroll
  for (int k = 0; k < BIN_EPB / 256; ++k) {
    int e = e0 + k * 256 + t;
    if (e < E) atomicAdd(&hist[edst[e] >> BKT_SHIFT], 1);
  }
  __syncthreads();
  // reserve: hist[b] becomes this block's running cursor (global base)
  for (int i = t; i < MAX_BKT; i += 256) {
    int c = hist[i];
    hist[i] = c ? atomicAdd(&gcursor[i], c) : 0;
  }
  __syncthreads();
#pragma unroll
  for (int k = 0; k < BIN_EPB / 256; ++k) {
    int e = e0 + k * 256 + t;
    if (e < E) {
      int d = edst[e];
      int b = d >> BKT_SHIFT;
      int pos = atomicAdd(&hist[b], 1);
      tmp_sw[pos] = make_int2(esrc[e], __float_as_int(ew[e]));
      tmp_d[pos] = (ushort)(d & (BKT_NODES - 1));
    }
  }
}

// binB: one block per bucket; LDS per-node cursors; dense region in -> dense
// region out (final CSR edge order).
__global__ __launch_bounds__(512) void binB_kernel(
    const int2* __restrict__ tmp_sw, const ushort* __restrict__ tmp_d,
    const int* __restrict__ rowptr, int2* __restrict__ ep, int M, int E) {
  __shared__ int cur[BKT_NODES];
  int b = blockIdx.x;
  int nbase = b * BKT_NODES;
  for (int i = threadIdx.x; i < BKT_NODES; i += 512) {
    int node = nbase + i;
    cur[i] = (node < M) ? rowptr[node] : 0;
  }
  __syncthreads();
  int start = rowptr[nbase];
  int nend = nbase + BKT_NODES;
  int end = (nend < M) ? rowptr[nend] : E;
  for (int i = start + threadIdx.x; i < end; i += 512) {
    int2 sw = tmp_sw[i];
    int dl = tmp_d[i];
    int pos = atomicAdd(&cur[dl], 1);
    ep[pos] = sw;
  }
}

// ---------------- SpMM1 (CSR): one WAVE per dst node ----------------------
// Wave split into halves: lanes 0-31 process even local edge indices, lanes
// 32-63 odd. Each lane owns 8 features (uint4 = 16B gather). Pair loop
// unrolled x4 -> up to 4 gathers (8 edges) in flight per wave. Out-of-range
// pair indices jj are provably <= 63 and hit preloaded mw=0 lanes (no-op).
// NOTE: macro params must not be named 'w' — '(UV).w' would get captured.
#define ACC8(UV, WT)                                            \
  acc[0] += (WT) * bflo((UV).x); acc[1] += (WT) * bfhi((UV).x); \
  acc[2] += (WT) * bflo((UV).y); acc[3] += (WT) * bfhi((UV).y); \
  acc[4] += (WT) * bflo((UV).z); acc[5] += (WT) * bfhi((UV).z); \
  acc[6] += (WT) * bflo((UV).w); acc[7] += (WT) * bfhi((UV).w);

__global__ __launch_bounds__(256) void spmm1_csr_kernel(
    const ushort* __restrict__ S, const int* __restrict__ rowptr,
    const int* __restrict__ deg, const int2* __restrict__ ep,
    const float* __restrict__ b1, ushort* __restrict__ h, int M) {
  int wid = (blockIdx.x * 256 + threadIdx.x) >> 6;
  int lane = threadIdx.x & 63;
  if (wid >= M) return;
  int beg = rowptr[wid];
  int n = deg[wid];
  int half = lane >> 5;
  int fl = lane & 31;                       // 8-feature block owner
  const ushort* Sl = S + (size_t)fl * 8;    // byte offset fl*16, 16B aligned
  float acc[8] = {};
  for (int j0 = 0; j0 < n; j0 += 64) {
    int cnt = min(64, n - j0);
    int msrc = 0;
    float mw = 0.f;
    if (lane < cnt) {
      int2 e = ep[beg + j0 + lane];
      msrc = e.x;
      mw = __int_as_float(e.y);
    }
    int pairs = (cnt + 1) >> 1;  // <= 32
    for (int p = 0; p < pairs; p += 4) {
      // jj = 2*(p+u)+half; p <= 28, u <= 3 -> jj <= 63 always.
      int jj0 = 2 * p + half;
      int s0 = __shfl(msrc, jj0);     float w0 = __shfl(mw, jj0);
      int s1 = __shfl(msrc, jj0 + 2); float w1 = __shfl(mw, jj0 + 2);
      int s2 = __shfl(msrc, jj0 + 4); float w2 = __shfl(mw, jj0 + 4);
      int s3 = __shfl(msrc, jj0 + 6); float w3 = __shfl(mw, jj0 + 6);
      uint4 u0 = *(const uint4*)(Sl + ((size_t)s0 << 8));
      uint4 u1 = *(const uint4*)(Sl + ((size_t)s1 << 8));
      uint4 u2 = *(const uint4*)(Sl + ((size_t)s2 << 8));
      uint4 u3 = *(const uint4*)(Sl + ((size_t)s3 << 8));
      ACC8(u0, w0)
      ACC8(u1, w1)
      ACC8(u2, w2)
      ACC8(u3, w3)
    }
  }
  // merge the two halves: lane l and l+32 hold partials of the same features
#pragma unroll
  for (int k = 0; k < 8; ++k) acc[k] += __shfl_xor(acc[k], 32);
  // each lane stores 4 bf16: features fl*8 + half*4 .. +3 (static selects,
  // no runtime array indexing -> stays in VGPRs)
  float a0 = half ? acc[4] : acc[0];
  float a1 = half ? acc[5] : acc[1];
  float a2 = half ? acc[6] : acc[2];
  float a3 = half ? acc[7] : acc[3];
  int fb = fl * 8 + half * 4;
  float4 b = *(const float4*)(b1 + fb);
  ushort4 o;
  o.x = f2bf(fmaxf(a0 + b.x, 0.f));
  o.y = f2bf(fmaxf(a1 + b.y, 0.f));
  o.z = f2bf(fmaxf(a2 + b.z, 0.f));
  o.w = f2bf(fmaxf(a3 + b.w, 0.f));
  *(ushort4*)(h + ((size_t)wid << 8) + fb) = o;
}

// ------------------- GEMM2: h(bf16) @ W2 -> bf16, W2 in LDS ---------------
__global__ __launch_bounds__(256) void gemm2_kernel(
    const ushort* __restrict__ H, const float* __restrict__ W2,
    ushort* __restrict__ S2, int M) {
  __shared__ float W2s[NHID * NCLASS];
  for (int i = threadIdx.x; i < NHID * NCLASS; i += 256) W2s[i] = W2[i];
  __syncthreads();
  int row = blockIdx.x * 256 + threadIdx.x;
  if (row >= M) return;
  const float4* W2v = (const float4*)W2s;
  float4 acc[10];
#pragma unroll
  for (int j = 0; j < 10; ++j) acc[j] = make_float4(0.f, 0.f, 0.f, 0.f);
  const uint4* hp = (const uint4*)(H + (size_t)row * NHID);
  for (int kb = 0; kb < 32; ++kb) {
    uint4 u = hp[kb];
    float a[8] = {bflo(u.x), bfhi(u.x), bflo(u.y), bfhi(u.y),
                  bflo(u.z), bfhi(u.z), bflo(u.w), bfhi(u.w)};
#pragma unroll
    for (int kk = 0; kk < 8; ++kk) {
#pragma unroll
      for (int j = 0; j < 10; ++j) {
        float4 wv = W2v[(kb * 8 + kk) * 10 + j];
        acc[j].x += a[kk] * wv.x;
        acc[j].y += a[kk] * wv.y;
        acc[j].z += a[kk] * wv.z;
        acc[j].w += a[kk] * wv.w;
      }
    }
  }
  uint2* outp = (uint2*)(S2 + (size_t)row * NCLASS);
#pragma unroll
  for (int j = 0; j < 10; j += 2) {
    uint2 o0, o1;
    o0.x = (unsigned)f2bf(acc[j].x) | ((unsigned)f2bf(acc[j].y) << 16);
    o0.y = (unsigned)f2bf(acc[j].z) | ((unsigned)f2bf(acc[j].w) << 16);
    o1.x = (unsigned)f2bf(acc[j + 1].x) | ((unsigned)f2bf(acc[j + 1].y) << 16);
    o1.y = (unsigned)f2bf(acc[j + 1].z) | ((unsigned)f2bf(acc[j + 1].w) << 16);
    outp[j] = o0;
    outp[j + 1] = o1;
  }
}

// -------- SpMM2 (CSR, bf16) + bias + log_softmax, one wave per node -------
// 3 edge-groups of 20 lanes (lanes 60-63 idle), each lane owns 2 classes.
// x2 unroll -> 6 edges / 2 loads in flight. Cross-group reduce via shfl.
__global__ __launch_bounds__(256) void spmm2_csr_kernel(
    const ushort* __restrict__ S2, const int* __restrict__ rowptr,
    const int* __restrict__ deg, const int2* __restrict__ ep,
    const float* __restrict__ b2, float* __restrict__ out, int M) {
  int wid = (blockIdx.x * 256 + threadIdx.x) >> 6;
  int lane = threadIdx.x & 63;
  if (wid >= M) return;
  int beg = rowptr[wid];
  int n = deg[wid];
  int g = (lane >= 40) ? 2 : ((lane >= 20) ? 1 : 0);
  bool act = lane < 60;
  int cl = lane - 20 * g;                 // class pair 0..19
  const ushort* S2l = S2 + cl * 2;
  float acc0 = 0.f, acc1 = 0.f;
  for (int j0 = 0; j0 < n; j0 += 64) {
    int cnt = min(64, n - j0);
    int msrc = 0;
    float mw = 0.f;
    if (lane < cnt) {
      int2 e = ep[beg + j0 + lane];
      msrc = e.x;
      mw = __int_as_float(e.y);
    }
    int trips = (cnt + 2) / 3;  // <= 22
    for (int p = 0; p < trips; p += 2) {
      int ja = 3 * p + g;       // may exceed 63 only via jb; mask anyway
      int jb = ja + 3;
      int sa = __shfl(msrc, ja & 63); float wa = __shfl(mw, ja & 63);
      int sb = __shfl(msrc, jb & 63); float wb = __shfl(mw, jb & 63);
      wa = (act && ja < cnt) ? wa : 0.f;
      wb = (act && jb < cnt) ? wb : 0.f;
      unsigned ua = *(const unsigned*)(S2l + (size_t)sa * NCLASS);
      unsigned ub = *(const unsigned*)(S2l + (size_t)sb * NCLASS);
      acc0 += wa * bflo(ua) + wb * bflo(ub);
      acc1 += wa * bfhi(ua) + wb * bfhi(ub);
    }
  }
  // reduce the 3 groups: totals land in lanes 0..19
  float r0a = __shfl(acc0, (lane + 20) & 63);
  float r0b = __shfl(acc0, (lane + 40) & 63);
  float r1a = __shfl(acc1, (lane + 20) & 63);
  float r1b = __shfl(acc1, (lane + 40) & 63);
  float v0 = -INFINITY, v1 = -INFINITY;
  if (lane < 20) {
    float2 b = *(const float2*)(b2 + lane * 2);
    v0 = acc0 + r0a + r0b + b.x;
    v1 = acc1 + r1a + r1b + b.y;
  }
  float m = fmaxf(v0, v1);
#pragma unroll
  for (int off = 32; off; off >>= 1) m = fmaxf(m, __shfl_xor(m, off));
  float ex = (lane < 20) ? __expf(v0 - m) + __expf(v1 - m) : 0.f;
  float s = ex;
#pragma unroll
  for (int off = 32; off; off >>= 1) s += __shfl_xor(s, off);
  float lse = m + __logf(s);
  if (lane < 20) {
    float2 o = {v0 - lse, v1 - lse};
    *(float2*)(out + (size_t)wid * NCLASS + lane * 2) = o;
  }
}

// ---------------------------------------------------------------------------
extern "C" void kernel_launch(void* const* d_in, const int* in_sizes, int n_in,
                              void* d_out, int out_size, void* d_ws,
                              size_t ws_size, hipStream_t stream) {
  const float* x  = (const float*)d_in[0];
  const int* esrc = (const int*)d_in[1];
  const int* edst = (const int*)d_in[2];
  const float* ew = (const float*)d_in[3];
  const float* W1 = (const float*)d_in[4];
  const float* b1 = (const float*)d_in[5];
  const float* W2 = (const float*)d_in[6];
  const float* b2 = (const float*)d_in[7];
  float* out = (float*)d_out;

  const int M = in_sizes[0] / NFEAT;  // 100000
  const int E = in_sizes[1];          // 3200000
  const int nbkt = (M + BKT_NODES - 1) / BKT_NODES;  // 196

  char* p = (char*)d_ws;
  ushort* support1 = (ushort*)p;           p += (size_t)M * NHID * 2;
  ushort* h        = (ushort*)p;           p += (size_t)M * NHID * 2;
  ushort* support2 = (ushort*)p;           p += (size_t)M * NCLASS * 2;
  ushort* W1t      = (ushort*)p;           p += (size_t)NFEAT * NHID * 2;
  int*    deg      = (int*)p;              p += (size_t)M * 4;
  int*    part     = (int*)p;              p += (size_t)M * 4;
  int*    rowptr   = (int*)p;              p += (size_t)M * 4;
  int*    gcursor  = (int*)p;              p += MAX_BKT * 4;
  int*    bsums    = (int*)p;              p += 512 * 4;
  int2*   ep       = (int2*)p;             p += (size_t)E * 8;
  int2*   tmp_sw   = (int2*)p;             p += (size_t)E * 8;
  ushort* tmp_d    = (ushort*)p;           // E * 2

  const int nbScan = (M + 255) / 256;  // 391 <= 512

  // ---- CSR build: hist -> rowptr -> bucketed counting sort ----
  hipMemsetAsync(deg, 0, (size_t)M * sizeof(int), stream);
  hist_kernel<<<(E + 255) / 256, 256, 0, stream>>>(edst, deg, E);
  scan1_kernel<<<nbScan, 256, 0, stream>>>(deg, part, bsums, M);
  scan2_kernel<<<1, 512, 0, stream>>>(bsums, nbScan);
  scan3_kernel<<<nbScan, 256, 0, stream>>>(part, bsums, deg, rowptr, M);
  initcur_kernel<<<1, 256, 0, stream>>>(rowptr, gcursor, nbkt);
  binA_kernel<<<(E + BIN_EPB - 1) / BIN_EPB, 256, 0, stream>>>(
      esrc, edst, ew, gcursor, tmp_sw, tmp_d, E);
  binB_kernel<<<nbkt, 512, 0, stream>>>(tmp_sw, tmp_d, rowptr, ep, M, E);

  // ---- layer 1 ----
  w1t_kernel<<<(NFEAT * NHID) / 256, 256, 0, stream>>>(W1, W1t);
  dim3 g1(NHID / 128, (M + 127) / 128);
  gemm1_mfma<<<g1, 256, 0, stream>>>(x, W1t, support1, M);
  spmm1_csr_kernel<<<(M * 64 + 255) / 256, 256, 0, stream>>>(
      support1, rowptr, deg, ep, b1, h, M);

  // ---- layer 2 ----
  gemm2_kernel<<<(M + 255) / 256, 256, 0, stream>>>(h, W2, support2, M);
  spmm2_csr_kernel<<<(M * 64 + 255) / 256, 256, 0, stream>>>(
      support2, rowptr, deg, ep, b2, out, M);
}